// Round 15
// baseline (280.285 us; speedup 1.0000x reference)
//
#include <hip/hip_runtime.h>
#include <hip/hip_bf16.h>
#include <math.h>

#define DD 1024
#define TT 2048
#define BB 2
#define HH 16
#define HDIM 64
#define HIDD 4096

typedef __attribute__((ext_vector_type(4))) float f32x4;
typedef __attribute__((ext_vector_type(8))) __bf16 bf16x8;
typedef __attribute__((ext_vector_type(4))) __bf16 bf16x4;

#define MF16 __builtin_amdgcn_mfma_f32_16x16x32_bf16

__device__ __forceinline__ void gload_lds16(const void* g, void* l) {
  __builtin_amdgcn_global_load_lds(
      (const __attribute__((address_space(1))) void*)g,
      (__attribute__((address_space(3))) void*)l, 16, 0, 0);
}

// ---------------- fused weight cast+transpose: all 4 weights, one launch ----------------
__global__ __launch_bounds__(256) void castAll(const float* __restrict__ Wqkv,
                                               const float* __restrict__ Wout,
                                               const float* __restrict__ W1,
                                               const float* __restrict__ W2,
                                               __bf16* __restrict__ WqkvT,
                                               __bf16* __restrict__ WoutT,
                                               __bf16* __restrict__ W1T,
                                               __bf16* __restrict__ W2T) {
  const int id = blockIdx.x;
  const float* W;
  __bf16* Wt;
  int K, N, gx, local;
  if (id < 768)        { W = Wqkv; Wt = WqkvT; K = 1024; N = 3072; gx = 48; local = id; }
  else if (id < 1024)  { W = Wout; Wt = WoutT; K = 1024; N = 1024; gx = 16; local = id - 768; }
  else if (id < 2048)  { W = W1;   Wt = W1T;   K = 1024; N = 4096; gx = 64; local = id - 1024; }
  else                 { W = W2;   Wt = W2T;   K = 4096; N = 1024; gx = 16; local = id - 2048; }
  const int n0 = (local % gx) * 64, k0 = (local / gx) * 64;
  __shared__ float t[64][65];
#pragma unroll
  for (int e = 0; e < 16; ++e) {
    int idx = e * 256 + threadIdx.x;
    int rr = idx >> 6, cc = idx & 63;
    t[rr][cc] = W[(size_t)(k0 + rr) * N + n0 + cc];
  }
  __syncthreads();
#pragma unroll
  for (int e = 0; e < 16; ++e) {
    int idx = e * 256 + threadIdx.x;
    int rr = idx >> 6, cc = idx & 63;
    Wt[(size_t)(n0 + rr) * K + k0 + cc] = (__bf16)t[cc][rr];
  }
}

// ---------------- layernorm -> bf16, one wave per row ----------------
__global__ __launch_bounds__(256) void ln_fwd(const float* __restrict__ x,
                                              const float* __restrict__ gamma,
                                              const float* __restrict__ beta,
                                              __bf16* __restrict__ out) {
  const int wave = threadIdx.x >> 6, lane = threadIdx.x & 63;
  const int row = blockIdx.x * 4 + wave;
  const float* xr = x + (size_t)row * DD;
  float4 v[4];
  float s = 0.0f, ss = 0.0f;
#pragma unroll
  for (int c = 0; c < 4; ++c) {
    v[c] = reinterpret_cast<const float4*>(xr)[c * 64 + lane];
    s += v[c].x + v[c].y + v[c].z + v[c].w;
    ss += v[c].x * v[c].x + v[c].y * v[c].y + v[c].z * v[c].z + v[c].w * v[c].w;
  }
#pragma unroll
  for (int m = 1; m <= 32; m <<= 1) { s += __shfl_xor(s, m); ss += __shfl_xor(ss, m); }
  const float mu = s * (1.0f / DD);
  const float rs = rsqrtf(ss * (1.0f / DD) - mu * mu + 1e-5f);
#pragma unroll
  for (int c = 0; c < 4; ++c) {
    const float4 gm = reinterpret_cast<const float4*>(gamma)[c * 64 + lane];
    const float4 bt = reinterpret_cast<const float4*>(beta)[c * 64 + lane];
    bf16x4 o;
    o[0] = (__bf16)((v[c].x - mu) * rs * gm.x + bt.x);
    o[1] = (__bf16)((v[c].y - mu) * rs * gm.y + bt.y);
    o[2] = (__bf16)((v[c].z - mu) * rs * gm.z + bt.z);
    o[3] = (__bf16)((v[c].w - mu) * rs * gm.w + bt.w);
    *reinterpret_cast<bf16x4*>(out + (size_t)row * DD + (c * 64 + lane) * 4) = o;
  }
}

// ================= 256x256 8-phase GEMM (T2+T3+T4+T5), BK=64 =================
// MODE 0: bf16 = acc+bias -> out0
// MODE 2: bf16 = gelu(acc+bias) -> out0
// MAP  1: producer map (1D grid 256) for W1.
template <int MODE, int MAP = 0>
__global__ __launch_bounds__(512, 1) void gemm8(const __bf16* __restrict__ A,
                                                const __bf16* __restrict__ Bt,
                                                const float* __restrict__ bias,
                                                void* __restrict__ out0,
                                                int N, int K, int kchunk) {
  const int tid = threadIdx.x;
  const int wid = tid >> 6, lane = tid & 63;
  const int g = lane >> 4, r = lane & 15;
  const int wrh = wid >> 2;
  const int wc = (wid & 3) * 64;

  int bm, bn;
  if constexpr (MAP == 1) {
    const int L = blockIdx.x;
    const int xcd = L & 7, idx = L >> 3;
    bm = (((xcd & 1) << 3) + (idx >> 2)) * 256;
    bn = (((xcd >> 1) << 2) + (idx & 3)) * 256;
  } else {
    const int gx = gridDim.x;
    const int nwg = gx * gridDim.y;
    const int orig = blockIdx.y * gx + blockIdx.x;
    const int swz = (orig & 7) * (nwg >> 3) + (orig >> 3);
    const int bn4 = swz & 3;
    const int bmt = (swz >> 2) % gx;
    const int bng = (swz >> 2) / gx;
    bm = bmt * 256;
    bn = (bng * 4 + bn4) * 256;
  }

  const int NT = kchunk >> 6;
  const __bf16* Asrc = A + (size_t)bm * K;
  const __bf16* Bsrc = Bt + (size_t)bn * K;

  __shared__ __bf16 lds[2][4][8192];  // 128 KB

  f32x4 acc[8][4] = {};
  bf16x8 bfr[4][2];

  auto STG = [&](int ab, int h, int kt) {
    const __bf16* src = (ab ? Bsrc : Asrc) + (size_t)h * 128 * K;
    char* dst = (char*)&lds[kt & 1][ab * 2 + h][0];
#pragma unroll
    for (int gl = 0; gl < 2; ++gl) {
      const int o = gl * 8192 + wid * 1024 + lane * 16;
      const int row = o >> 7;
      const int cbs = (o & 127) ^ (((row >> 2) & 1) << 5);
      gload_lds16((const char*)src + (size_t)row * (K * 2) + kt * 128 + cbs,
                  dst + gl * 8192 + wid * 1024);
    }
  };
  auto DSA = [&](int s, int mi, int kk) -> bf16x8 {
    return *(const bf16x8*)((const char*)&lds[s][wrh][0] + (mi * 16 + r) * 128 +
                            ((kk * 64 + g * 16) ^ ((r & 4) << 3)));
  };
  auto DSB = [&](int s, int nj, int kk) -> bf16x8 {
    const int rt = wc + nj * 16 + r;
    return *(const bf16x8*)((const char*)&lds[s][2 + (rt >> 7)][0] + (rt & 127) * 128 +
                            ((kk * 64 + g * 16) ^ ((r & 4) << 3)));
  };

#define PH(S, Q, STAGE_STMT, WAIT_STMT)                                        \
  {                                                                            \
    if (Q == 0) {                                                              \
      _Pragma("unroll") for (int nj = 0; nj < 4; ++nj) {                       \
        bfr[nj][0] = DSB(S, nj, 0);                                            \
        bfr[nj][1] = DSB(S, nj, 1);                                            \
      }                                                                        \
    }                                                                          \
    bf16x8 a00 = DSA(S, 2 * Q, 0), a01 = DSA(S, 2 * Q, 1);                     \
    bf16x8 a10 = DSA(S, 2 * Q + 1, 0), a11 = DSA(S, 2 * Q + 1, 1);             \
    STAGE_STMT;                                                                \
    WAIT_STMT;                                                                 \
    __builtin_amdgcn_s_barrier();                                              \
    asm volatile("s_waitcnt lgkmcnt(0)" ::: "memory");                         \
    __builtin_amdgcn_s_setprio(1);                                             \
    _Pragma("unroll") for (int nj = 0; nj < 4; ++nj) {                         \
      acc[2 * Q][nj] = MF16(a00, bfr[nj][0], acc[2 * Q][nj], 0, 0, 0);         \
      acc[2 * Q][nj] = MF16(a01, bfr[nj][1], acc[2 * Q][nj], 0, 0, 0);         \
      acc[2 * Q + 1][nj] = MF16(a10, bfr[nj][0], acc[2 * Q + 1][nj], 0, 0, 0); \
      acc[2 * Q + 1][nj] = MF16(a11, bfr[nj][1], acc[2 * Q + 1][nj], 0, 0, 0); \
    }                                                                          \
    __builtin_amdgcn_s_setprio(0);                                             \
    __builtin_amdgcn_s_barrier();                                              \
  }

  STG(1, 0, 0); STG(1, 1, 0); STG(0, 0, 0); STG(0, 1, 0);
  STG(1, 0, 1); STG(1, 1, 1); STG(0, 0, 1);
  asm volatile("s_waitcnt vmcnt(6)" ::: "memory");
  __builtin_amdgcn_s_barrier();

  const int NI = NT >> 1;
  for (int i = 0; i < NI; ++i) {
    const int k2 = 2 * i + 2, k3 = 2 * i + 3;
    const bool nl = (i + 1 < NI);
    PH(0, 0, { STG(0, 1, 2 * i + 1); }, {});
    PH(0, 1, { if (nl) STG(1, 0, k2); }, {});
    PH(0, 2, { if (nl) STG(1, 1, k2); }, {});
    PH(0, 3, { if (nl) STG(0, 0, k2); },
       { if (nl) asm volatile("s_waitcnt vmcnt(6)" ::: "memory");
         else    asm volatile("s_waitcnt vmcnt(0)" ::: "memory"); });
    PH(1, 0, { if (nl) STG(0, 1, k2); }, {});
    PH(1, 1, { if (nl) STG(1, 0, k3); }, {});
    PH(1, 2, { if (nl) STG(1, 1, k3); }, {});
    PH(1, 3, { if (nl) STG(0, 0, k3); },
       { if (nl) asm volatile("s_waitcnt vmcnt(6)" ::: "memory"); });
  }
#undef PH

  const int row0 = bm + wrh * 128 + g * 4;
  const int col0 = bn + wc + r;
#pragma unroll
  for (int mi = 0; mi < 8; ++mi) {
#pragma unroll
    for (int nj = 0; nj < 4; ++nj) {
      const int col = col0 + nj * 16;
      const float bv = bias[col];
#pragma unroll
      for (int i4 = 0; i4 < 4; ++i4) {
        const int rowg = row0 + mi * 16 + i4;
        const size_t idx = (size_t)rowg * N + col;
        const float v = acc[mi][nj][i4];
        if constexpr (MODE == 0) {
          ((__bf16*)out0)[idx] = (__bf16)(v + bv);
        } else {
          const float t = v + bv;
          const float u2 = t * (1.5957691216f + t * t * 0.0713548163f);
          ((__bf16*)out0)[idx] = (__bf16)(t * __builtin_amdgcn_rcpf(1.0f + __expf(-u2)));
        }
      }
    }
  }
}

// ================= W2 GEMM: 2-phase, 128x256 tile, split-K4 z-aware =================
// out[M=4096][N=1024] partial sums over K=4096 in 4 chunks of 1024.
// grid 512 (1D): xcd=L&7 -> zz=xcd>>1 (k-chunk), m-half=xcd&1; idx>>2 = m-tile(16), idx&3 = n-tile(4).
// zz==0 -> plain fp32 to out; zz=1..3 -> bf16 partial to q1/q2/q3 (reduceW2 folds x1+b2).
__global__ __launch_bounds__(256) void gemm_w2(const __bf16* __restrict__ A,
                                               const __bf16* __restrict__ Bt,
                                               void* __restrict__ out0,
                                               __bf16* __restrict__ q1,
                                               __bf16* __restrict__ q2,
                                               __bf16* __restrict__ q3) {
  const int K = 4096, N = 1024;
  __shared__ __bf16 As[128 * 32];  // 8 KB
  __shared__ __bf16 Bs[256 * 32];  // 16 KB
  const int tid = threadIdx.x;
  const int wave = tid >> 6, lane = tid & 63;
  const int g = lane >> 4, r = lane & 15;

  const int L = blockIdx.x;
  const int xcd = L & 7, idx = L >> 3;
  const int zz = xcd >> 1;
  const int bm = (((xcd & 1) << 4) + (idx >> 2)) * 128;  // 32 m-tiles
  const int bn = (idx & 3) * 256;                        // 4 n-tiles
  const int kbase = zz * 1024;

  f32x4 acc[4][8] = {};

  // A staging: identical pattern to gemm_bt (2 loads/thread over 8KB)
  const int off0 = wave * 2048 + lane * 16;
  const int off1 = off0 + 1024;
  const int sr0 = off0 >> 6, sk0 = (off0 & 63) >> 1;
  const int sr1 = off1 >> 6, sk1 = (off1 & 63) >> 1;
  const __bf16* gA0 = A + (size_t)(bm + sr0) * K + kbase + sk0;
  const __bf16* gA1 = A + (size_t)(bm + sr1) * K + kbase + sk1;
  char* lA0 = (char*)As + wave * 2048;
  char* lA1 = lA0 + 1024;
  // B staging: 16KB, 4 loads/thread; (wave,q) covers rows wave*64+q*16 .. +15
  const __bf16* gB[4];
  char* lB[4];
#pragma unroll
  for (int q = 0; q < 4; ++q) {
    const int ob = wave * 4096 + q * 1024 + lane * 16;
    const int rb = ob >> 6, kb = (ob & 63) >> 1;
    gB[q] = Bt + (size_t)(bn + rb) * K + kbase + kb;
    lB[q] = (char*)Bs + wave * 4096 + q * 1024;
  }

  const int mh = wave >> 1;  // wave's m-half (64 rows)
  const int nh = wave & 1;   // wave's n-half (128 cols)

  for (int k0 = 0; k0 < 1024; k0 += 32) {
    gload_lds16(gA0 + k0, lA0);
    gload_lds16(gA1 + k0, lA1);
#pragma unroll
    for (int q = 0; q < 4; ++q) gload_lds16(gB[q] + k0, lB[q]);
    __syncthreads();
    bf16x8 af[4], bf[8];
#pragma unroll
    for (int mi = 0; mi < 4; ++mi)
      af[mi] = *reinterpret_cast<const bf16x8*>(&As[(mh * 64 + mi * 16 + r) * 32 + g * 8]);
#pragma unroll
    for (int ni = 0; ni < 8; ++ni)
      bf[ni] = *reinterpret_cast<const bf16x8*>(&Bs[(nh * 128 + ni * 16 + r) * 32 + g * 8]);
    __builtin_amdgcn_s_setprio(1);
#pragma unroll
    for (int mi = 0; mi < 4; ++mi)
#pragma unroll
      for (int ni = 0; ni < 8; ++ni)
        acc[mi][ni] = MF16(af[mi], bf[ni], acc[mi][ni], 0, 0, 0);
    __builtin_amdgcn_s_setprio(0);
    __syncthreads();
  }

  const int row0 = bm + mh * 64 + 4 * g;
  const int col0 = bn + nh * 128 + r;
#pragma unroll
  for (int mi = 0; mi < 4; ++mi) {
#pragma unroll
    for (int ni = 0; ni < 8; ++ni) {
      const int col = col0 + ni * 16;
#pragma unroll
      for (int i = 0; i < 4; ++i) {
        const int row = row0 + mi * 16 + i;
        const size_t idx2 = (size_t)row * N + col;
        const float v = acc[mi][ni][i];
        if (zz == 0) {
          ((float*)out0)[idx2] = v;
        } else {
          __bf16* p = (zz == 1 ? q1 : (zz == 2 ? q2 : q3));
          p[idx2] = (__bf16)v;
        }
      }
    }
  }
}

// ---------------- W2 split-K reduce: out = out(p0) + x1 + b2 + p1+p2+p3 ----------------
__global__ __launch_bounds__(256) void reduceW2(const __bf16* __restrict__ p1,
                                                const __bf16* __restrict__ p2,
                                                const __bf16* __restrict__ p3,
                                                const float* __restrict__ x1,
                                                const float* __restrict__ b2,
                                                float* __restrict__ out) {
  const size_t i8 = ((size_t)blockIdx.x * 256 + threadIdx.x) * 8;
  const int col0 = (int)(i8 & 1023);
  bf16x8 a = *(const bf16x8*)(p1 + i8);
  bf16x8 b = *(const bf16x8*)(p2 + i8);
  bf16x8 c = *(const bf16x8*)(p3 + i8);
  float4 o0 = *(const float4*)(out + i8);
  float4 o1 = *(const float4*)(out + i8 + 4);
  const float4 xv0 = *(const float4*)(x1 + i8);
  const float4 xv1 = *(const float4*)(x1 + i8 + 4);
  const float4 bb0 = *(const float4*)(b2 + col0);
  const float4 bb1 = *(const float4*)(b2 + col0 + 4);
  float* op0 = (float*)&o0;
  float* op1 = (float*)&o1;
  const float* xp0 = (const float*)&xv0;
  const float* xp1 = (const float*)&xv1;
  const float* bp0 = (const float*)&bb0;
  const float* bp1 = (const float*)&bb1;
#pragma unroll
  for (int j = 0; j < 4; ++j)
    op0[j] += xp0[j] + bp0[j] + (float)a[j] + (float)b[j] + (float)c[j];
#pragma unroll
  for (int j = 0; j < 4; ++j)
    op1[j] += xp1[j] + bp1[j] + (float)a[4 + j] + (float)b[4 + j] + (float)c[4 + j];
  *(float4*)(out + i8) = o0;
  *(float4*)(out + i8 + 4) = o1;
}

// ---------------- 2-phase 128^2 GEMM (wout): MODE 1 fp32 +resid ----------------
template <int MODE>
__global__ __launch_bounds__(256) void gemm_bt(const __bf16* __restrict__ A,
                                               const __bf16* __restrict__ Bt,
                                               const float* __restrict__ bias,
                                               const float* __restrict__ resid,
                                               void* __restrict__ Cout,
                                               int M, int N, int K) {
  __shared__ __bf16 As[128 * 32];
  __shared__ __bf16 Bs[128 * 32];
  const int tid = threadIdx.x;
  const int wave = tid >> 6, lane = tid & 63;
  const int g = lane >> 4, r = lane & 15;
  const int gx = gridDim.x;
  const int nwg = gx * gridDim.y;
  const int orig = blockIdx.y * gx + blockIdx.x;
  const int swz = (orig & 7) * (nwg >> 3) + (orig >> 3);
  const int bn4 = swz & 3;
  const int bmt = (swz >> 2) % gx;
  const int bng = (swz >> 2) / gx;
  const int bm = bmt * 128;
  const int bn = (bng * 4 + bn4) * 128;
  const int wr = (wave >> 1) * 64, wc = (wave & 1) * 64;
  f32x4 acc[4][4] = {};

  const int off0 = wave * 2048 + lane * 16;
  const int off1 = off0 + 1024;
  const int sr0 = off0 >> 6, sk0 = (off0 & 63) >> 1;
  const int sr1 = off1 >> 6, sk1 = (off1 & 63) >> 1;
  const __bf16* gA0 = A + (size_t)(bm + sr0) * K + sk0;
  const __bf16* gA1 = A + (size_t)(bm + sr1) * K + sk1;
  const __bf16* gB0 = Bt + (size_t)(bn + sr0) * K + sk0;
  const __bf16* gB1 = Bt + (size_t)(bn + sr1) * K + sk1;
  char* lA0 = (char*)As + wave * 2048;
  char* lA1 = lA0 + 1024;
  char* lB0 = (char*)Bs + wave * 2048;
  char* lB1 = lB0 + 1024;

  for (int k0 = 0; k0 < K; k0 += 32) {
    gload_lds16(gA0 + k0, lA0);
    gload_lds16(gA1 + k0, lA1);
    gload_lds16(gB0 + k0, lB0);
    gload_lds16(gB1 + k0, lB1);
    __syncthreads();
    bf16x8 af[4], bf[4];
#pragma unroll
    for (int mi = 0; mi < 4; ++mi)
      af[mi] = *reinterpret_cast<const bf16x8*>(&As[(wr + mi * 16 + r) * 32 + g * 8]);
#pragma unroll
    for (int ni = 0; ni < 4; ++ni)
      bf[ni] = *reinterpret_cast<const bf16x8*>(&Bs[(wc + ni * 16 + r) * 32 + g * 8]);
    __builtin_amdgcn_s_setprio(1);
#pragma unroll
    for (int mi = 0; mi < 4; ++mi)
#pragma unroll
      for (int ni = 0; ni < 4; ++ni)
        acc[mi][ni] = MF16(af[mi], bf[ni], acc[mi][ni], 0, 0, 0);
    __builtin_amdgcn_s_setprio(0);
    __syncthreads();
  }

  const int row0 = bm + wr + 4 * g;
  const int col0 = bn + wc + r;
#pragma unroll
  for (int mi = 0; mi < 4; ++mi) {
#pragma unroll
    for (int ni = 0; ni < 4; ++ni) {
      const int col = col0 + ni * 16;
      const float bv = bias[col];
#pragma unroll
      for (int i = 0; i < 4; ++i) {
        const int row = row0 + mi * 16 + i;
        const size_t idx = (size_t)row * N + col;
        float v = acc[mi][ni][i] + bv;
        if (MODE == 0) {
          ((__bf16*)Cout)[idx] = (__bf16)v;
        } else if (MODE == 1) {
          ((float*)Cout)[idx] = v + resid[idx];
        } else {
          const float u2 = v * (1.5957691216f + v * v * 0.0713548163f);
          const float gl = v * __builtin_amdgcn_rcpf(1.0f + __expf(-u2));
          ((__bf16*)Cout)[idx] = (__bf16)gl;
        }
      }
    }
  }
}

// ---------------- V^T precompute: vtg[bh][d][t] = V[b,t,h,d] ----------------
__global__ __launch_bounds__(256) void vtrans(const __bf16* __restrict__ qkv,
                                              __bf16* __restrict__ vtg) {
  const int bh = blockIdx.y, b = bh >> 4, h = bh & 15;
  const int t0 = blockIdx.x * 64;
  const int tid = threadIdx.x, wave = tid >> 6, lane = tid & 63;
  __shared__ __bf16 tile[64 * 64];
#pragma unroll
  for (int e = 0; e < 2; ++e) {
    const int gid = e * 256 + tid;
    const int row = gid >> 3, d0 = (gid & 7) * 8;
    bf16x8 v = *reinterpret_cast<const bf16x8*>(
        qkv + (size_t)(b * TT + t0 + row) * 3072 + 2048 + h * 64 + d0);
    const int slot = (d0 >> 3) ^ (row & 7);
    *reinterpret_cast<bf16x8*>((char*)tile + row * 128 + slot * 16) = v;
  }
  __syncthreads();
  const int d = lane;
#pragma unroll
  for (int e = 0; e < 2; ++e) {
    const int k0 = (wave * 2 + e) * 8;
    bf16x8 o;
#pragma unroll
    for (int j = 0; j < 8; ++j) {
      const int row = k0 + j;
      o[j] = *(const __bf16*)((const char*)tile + row * 128 +
                              (((d >> 3) ^ (row & 7)) << 4) + (d & 7) * 2);
    }
    *reinterpret_cast<bf16x8*>(&vtg[((size_t)bh * 64 + d) * 2048 + t0 + k0]) = o;
  }
}

// ---------------- stage one 8KB [2][64][32]-panel tile via global_load_lds ----------------
__device__ __forceinline__ void stage_kv(const __bf16* __restrict__ src_row0, int rstride,
                                         int wave, int lane, char* tile) {
#pragma unroll
  for (int qq = 0; qq < 2; ++qq) {
    const int o = wave * 2048 + qq * 1024 + lane * 16;
    const int p = o >> 12, row = (o >> 6) & 63, cb = (o >> 4) & 3;
    gload_lds16(src_row0 + (size_t)row * rstride + p * 32 + cb * 8,
                tile + wave * 2048 + qq * 1024);
  }
}

// ---------------- causal flash attention, q-tile 64, mirror-paired, XCD-local bh ----------------
__global__ __launch_bounds__(256) void attn_fwd(const __bf16* __restrict__ qkv,
                                                const __bf16* __restrict__ vtg,
                                                __bf16* __restrict__ atto) {
  const int orig = blockIdx.y * gridDim.x + blockIdx.x;
  const int swz = (orig & 7) * 64 + (orig >> 3);
  const int bh = swz >> 4;
  const int j = swz & 15;
  const int b = bh >> 4, h = bh & 15;
  const int tid = threadIdx.x;
  const int wave = tid >> 6, lane = tid & 63;
  const int g = lane >> 4, r = lane & 15;

  __shared__ __bf16 Qs[2 * 64 * 32];
  __shared__ __bf16 Ks[2][2 * 64 * 32];
  __shared__ __bf16 Vs[2][2 * 64 * 32];
  __shared__ __bf16 Pl[4][2 * 16 * 32];

  const __bf16* ksrc = qkv + (size_t)(b * TT) * 3072 + 1024 + h * 64;
  const __bf16* vsrc = vtg + (size_t)bh * 64 * 2048;
  const float C2 = 0.18033688011112042f;  // 0.125 * log2(e)

  for (int ph = 0; ph < 2; ++ph) {
    const int qt = ph ? (31 - j) : j;
    const int q0 = qt * 64;
    stage_kv(qkv + (size_t)(b * TT + q0) * 3072 + h * 64, 3072, wave, lane, (char*)Qs);
    stage_kv(ksrc, 3072, wave, lane, (char*)Ks[0]);
    stage_kv(vsrc, 2048, wave, lane, (char*)Vs[0]);

    f32x4 oacc[4] = {};
    float m_s[4], l_s[4];
#pragma unroll
    for (int i = 0; i < 4; ++i) { m_s[i] = -1e30f; l_s[i] = 0.0f; }

    const int nt = qt + 1;
    int cur = 0;
    for (int t = 0; t < nt; ++t) {
      const int kv0 = t * 64;
      __syncthreads();
      if (t + 1 < nt) {
        stage_kv(ksrc + (size_t)(kv0 + 64) * 3072, 3072, wave, lane, (char*)Ks[cur ^ 1]);
        stage_kv(vsrc + kv0 + 64, 2048, wave, lane, (char*)Vs[cur ^ 1]);
      }
      bf16x8 qf[2];
#pragma unroll
      for (int kp = 0; kp < 2; ++kp)
        qf[kp] = *reinterpret_cast<const bf16x8*>(&Qs[kp * 2048 + (wave * 16 + r) * 32 + g * 8]);
      f32x4 s[4];
#pragma unroll
      for (int cn = 0; cn < 4; ++cn) s[cn] = f32x4{0.f, 0.f, 0.f, 0.f};
      __builtin_amdgcn_s_setprio(1);
#pragma unroll
      for (int cn = 0; cn < 4; ++cn)
#pragma unroll
        for (int kp = 0; kp < 2; ++kp) {
          bf16x8 bk = *reinterpret_cast<const bf16x8*>(
              &Ks[cur][kp * 2048 + (cn * 16 + r) * 32 + g * 8]);
          s[cn] = MF16(qf[kp], bk, s[cn], 0, 0, 0);
        }
      __builtin_amdgcn_s_setprio(0);
      const int rowg = q0 + wave * 16 + 4 * g;
      float pm[4];
#pragma unroll
      for (int i = 0; i < 4; ++i) pm[i] = -1e30f;
      if (kv0 + 63 > q0 + wave * 16) {
#pragma unroll
        for (int cn = 0; cn < 4; ++cn) {
          const int colg = kv0 + cn * 16 + r;
#pragma unroll
          for (int i = 0; i < 4; ++i) {
            float v = s[cn][i] * C2;
            v = (colg > rowg + i) ? -1e30f : v;
            s[cn][i] = v;
            pm[i] = fmaxf(pm[i], v);
          }
        }
      } else {
#pragma unroll
        for (int cn = 0; cn < 4; ++cn)
#pragma unroll
          for (int i = 0; i < 4; ++i) {
            const float v = s[cn][i] * C2;
            s[cn][i] = v;
            pm[i] = fmaxf(pm[i], v);
          }
      }
      const int upd = __any((pm[0] > m_s[0] + 8.0f) || (pm[1] > m_s[1] + 8.0f) ||
                            (pm[2] > m_s[2] + 8.0f) || (pm[3] > m_s[3] + 8.0f));
      if (upd) {
#pragma unroll
        for (int i = 0; i < 4; ++i) {
          pm[i] = fmaxf(pm[i], __shfl_xor(pm[i], 1));
          pm[i] = fmaxf(pm[i], __shfl_xor(pm[i], 2));
          pm[i] = fmaxf(pm[i], __shfl_xor(pm[i], 4));
          pm[i] = fmaxf(pm[i], __shfl_xor(pm[i], 8));
          const float mn = fmaxf(m_s[i], pm[i]);
          const float sf = __builtin_amdgcn_exp2f(m_s[i] - mn);
          m_s[i] = mn;
          l_s[i] *= sf;
#pragma unroll
          for (int ni = 0; ni < 4; ++ni) oacc[ni][i] *= sf;
        }
      }
#pragma unroll
      for (int cn = 0; cn < 4; ++cn)
#pragma unroll
        for (int i = 0; i < 4; ++i) {
          const float p = __builtin_amdgcn_exp2f(s[cn][i] - m_s[i]);
          s[cn][i] = p;
          l_s[i] += p;
        }
#pragma unroll
      for (int cn = 0; cn < 4; ++cn)
#pragma unroll
        for (int i = 0; i < 4; ++i) {
          const int row = 4 * g + i;
          const int byteoff = (cn >> 1) * 1024 +
              ((row * 64 + (cn & 1) * 32 + r * 2) ^ ((row & 7) << 4));
          *(__bf16*)((char*)&Pl[wave][0] + byteoff) = (__bf16)s[cn][i];
        }
      bf16x8 pa[2];
#pragma unroll
      for (int kp = 0; kp < 2; ++kp) {
        const int byteoff = kp * 1024 + ((r * 64 + g * 16) ^ ((r & 7) << 4));
        pa[kp] = *reinterpret_cast<const bf16x8*>((const char*)&Pl[wave][0] + byteoff);
      }
      __builtin_amdgcn_s_setprio(1);
#pragma unroll
      for (int ni = 0; ni < 4; ++ni)
#pragma unroll
        for (int kp = 0; kp < 2; ++kp) {
          bf16x8 bv = *reinterpret_cast<const bf16x8*>(
              &Vs[cur][kp * 2048 + (ni * 16 + r) * 32 + g * 8]);
          oacc[ni] = MF16(pa[kp], bv, oacc[ni], 0, 0, 0);
        }
      __builtin_amdgcn_s_setprio(0);
      cur ^= 1;
    }

#pragma unroll
    for (int i = 0; i < 4; ++i) {
      float l = l_s[i];
      l += __shfl_xor(l, 1);
      l += __shfl_xor(l, 2);
      l += __shfl_xor(l, 4);
      l += __shfl_xor(l, 8);
      const float inv = 1.0f / l;
      const size_t rowo = (size_t)(b * TT + q0 + wave * 16 + 4 * g + i) * DD + h * 64;
#pragma unroll
      for (int ni = 0; ni < 4; ++ni)
        atto[rowo + ni * 16 + r] = (__bf16)(oacc[ni][i] * inv);
    }
    __syncthreads();
  }
}

extern "C" void kernel_launch(void* const* d_in, const int* in_sizes, int n_in,
                              void* d_out, int out_size, void* d_ws, size_t ws_size,
                              hipStream_t stream) {
  const float* x     = (const float*)d_in[0];
  const float* ln1_g = (const float*)d_in[1];
  const float* ln1_b = (const float*)d_in[2];
  const float* Wqkv  = (const float*)d_in[3];
  const float* bqkv  = (const float*)d_in[4];
  const float* Wout  = (const float*)d_in[5];
  const float* bout  = (const float*)d_in[6];
  const float* ln2_g = (const float*)d_in[7];
  const float* ln2_b = (const float*)d_in[8];
  const float* W1    = (const float*)d_in[9];
  const float* b1    = (const float*)d_in[10];
  const float* W2    = (const float*)d_in[11];
  const float* b2    = (const float*)d_in[12];
  float* out = (float*)d_out;

  char* ws = (char*)d_ws;
  const size_t MB = 1024 * 1024;
  __bf16* WqkvT = (__bf16*)(ws);             // 0-6 MB
  __bf16* WoutT = (__bf16*)(ws + 6 * MB);    // 6-8 MB
  __bf16* W1T   = (__bf16*)(ws + 8 * MB);    // 8-16 MB
  __bf16* W2T   = (__bf16*)(ws + 16 * MB);   // 16-24 MB
  float*  x1    = (float*)(ws + 24 * MB);    // 24-40 MB fp32 (written by wout gemm)
  __bf16* vtg   = (__bf16*)(ws + 24 * MB);   // 24-32 MB — dead before x1 written
  __bf16* hbuf  = (__bf16*)(ws + 40 * MB);   // 40-48 MB (ln1/ln2 out)
  __bf16* qkvb  = (__bf16*)(ws + 48 * MB);   // 48-72 MB
  __bf16* atto  = (__bf16*)(ws + 72 * MB);   // 72-80 MB
  __bf16* mlp1  = (__bf16*)(ws + 48 * MB);   // 48-80 MB (aliases qkvb+atto, dead by then)
  __bf16* p1b   = (__bf16*)(ws);             // 0-8 MB   (WqkvT/WoutT dead)
  __bf16* p2b   = (__bf16*)(ws + 8 * MB);    // 8-16 MB  (W1T dead)
  __bf16* p3b   = (__bf16*)(ws + 40 * MB);   // 40-48 MB (hbuf dead after W1 gemm)

  // weight prep (single launch)
  castAll<<<3072, 256, 0, stream>>>(Wqkv, Wout, W1, W2, WqkvT, WoutT, W1T, W2T);

  // attention path
  ln_fwd<<<1024, 256, 0, stream>>>(x, ln1_g, ln1_b, hbuf);
  gemm8<0><<<dim3(16, 12), 512, 0, stream>>>(hbuf, WqkvT, bqkv, qkvb, 3072, 1024, 1024);
  vtrans<<<dim3(32, 32), 256, 0, stream>>>(qkvb, vtg);
  attn_fwd<<<dim3(16, 32), 256, 0, stream>>>(qkvb, vtg, atto);
  gemm_bt<1><<<dim3(32, 8), 256, 0, stream>>>(atto, WoutT, bout, x, x1, 4096, 1024, 1024);

  // MLP path
  ln_fwd<<<1024, 256, 0, stream>>>(x1, ln2_g, ln2_b, hbuf);
  gemm8<2, 1><<<256, 512, 0, stream>>>(hbuf, W1T, b1, mlp1, 4096, 1024, 1024);
  gemm_w2<<<512, 256, 0, stream>>>(mlp1, W2T, out, p1b, p2b, p3b);
  reduceW2<<<2048, 256, 0, stream>>>(p1b, p2b, p3b, x1, b2, out);
}

// Round 16
// 232.562 us; speedup vs baseline: 1.2052x; 1.2052x over previous
//
#include <hip/hip_runtime.h>
#include <hip/hip_bf16.h>
#include <math.h>

#define DD 1024
#define TT 2048
#define BB 2
#define HH 16
#define HDIM 64
#define HIDD 4096

typedef __attribute__((ext_vector_type(4))) float f32x4;
typedef __attribute__((ext_vector_type(8))) __bf16 bf16x8;
typedef __attribute__((ext_vector_type(4))) __bf16 bf16x4;

#define MF16 __builtin_amdgcn_mfma_f32_16x16x32_bf16

__device__ __forceinline__ void gload_lds16(const void* g, void* l) {
  __builtin_amdgcn_global_load_lds(
      (const __attribute__((address_space(1))) void*)g,
      (__attribute__((address_space(3))) void*)l, 16, 0, 0);
}

// ---------------- fused weight cast+transpose: all 4 weights, one launch ----------------
__global__ __launch_bounds__(256) void castAll(const float* __restrict__ Wqkv,
                                               const float* __restrict__ Wout,
                                               const float* __restrict__ W1,
                                               const float* __restrict__ W2,
                                               __bf16* __restrict__ WqkvT,
                                               __bf16* __restrict__ WoutT,
                                               __bf16* __restrict__ W1T,
                                               __bf16* __restrict__ W2T) {
  const int id = blockIdx.x;
  const float* W;
  __bf16* Wt;
  int K, N, gx, local;
  if (id < 768)        { W = Wqkv; Wt = WqkvT; K = 1024; N = 3072; gx = 48; local = id; }
  else if (id < 1024)  { W = Wout; Wt = WoutT; K = 1024; N = 1024; gx = 16; local = id - 768; }
  else if (id < 2048)  { W = W1;   Wt = W1T;   K = 1024; N = 4096; gx = 64; local = id - 1024; }
  else                 { W = W2;   Wt = W2T;   K = 4096; N = 1024; gx = 16; local = id - 2048; }
  const int n0 = (local % gx) * 64, k0 = (local / gx) * 64;
  __shared__ float t[64][65];
#pragma unroll
  for (int e = 0; e < 16; ++e) {
    int idx = e * 256 + threadIdx.x;
    int rr = idx >> 6, cc = idx & 63;
    t[rr][cc] = W[(size_t)(k0 + rr) * N + n0 + cc];
  }
  __syncthreads();
#pragma unroll
  for (int e = 0; e < 16; ++e) {
    int idx = e * 256 + threadIdx.x;
    int rr = idx >> 6, cc = idx & 63;
    Wt[(size_t)(n0 + rr) * K + k0 + cc] = (__bf16)t[cc][rr];
  }
}

// ---------------- layernorm -> bf16, one wave per row ----------------
__global__ __launch_bounds__(256) void ln_fwd(const float* __restrict__ x,
                                              const float* __restrict__ gamma,
                                              const float* __restrict__ beta,
                                              __bf16* __restrict__ out) {
  const int wave = threadIdx.x >> 6, lane = threadIdx.x & 63;
  const int row = blockIdx.x * 4 + wave;
  const float* xr = x + (size_t)row * DD;
  float4 v[4];
  float s = 0.0f, ss = 0.0f;
#pragma unroll
  for (int c = 0; c < 4; ++c) {
    v[c] = reinterpret_cast<const float4*>(xr)[c * 64 + lane];
    s += v[c].x + v[c].y + v[c].z + v[c].w;
    ss += v[c].x * v[c].x + v[c].y * v[c].y + v[c].z * v[c].z + v[c].w * v[c].w;
  }
#pragma unroll
  for (int m = 1; m <= 32; m <<= 1) { s += __shfl_xor(s, m); ss += __shfl_xor(ss, m); }
  const float mu = s * (1.0f / DD);
  const float rs = rsqrtf(ss * (1.0f / DD) - mu * mu + 1e-5f);
#pragma unroll
  for (int c = 0; c < 4; ++c) {
    const float4 gm = reinterpret_cast<const float4*>(gamma)[c * 64 + lane];
    const float4 bt = reinterpret_cast<const float4*>(beta)[c * 64 + lane];
    bf16x4 o;
    o[0] = (__bf16)((v[c].x - mu) * rs * gm.x + bt.x);
    o[1] = (__bf16)((v[c].y - mu) * rs * gm.y + bt.y);
    o[2] = (__bf16)((v[c].z - mu) * rs * gm.z + bt.z);
    o[3] = (__bf16)((v[c].w - mu) * rs * gm.w + bt.w);
    *reinterpret_cast<bf16x4*>(out + (size_t)row * DD + (c * 64 + lane) * 4) = o;
  }
}

// ================= 256x256 8-phase GEMM (T2+T3+T4+T5), BK=64 =================
// MODE 0: bf16 = acc+bias -> out0
// MODE 2: bf16 = gelu(acc+bias) -> out0
// MODE 3: split-K, z-aware XCD map; z==0 -> plain fp32 acc to out0 (overwrite);
//         z==1..3 -> bf16 partial to q1/q2/q3. bias/resid folded by reduceW2.
// MAP  1: producer map for W1 (1D grid 256).
template <int MODE, int MAP = 0>
__global__ __launch_bounds__(512, 1) void gemm8(const __bf16* __restrict__ A,
                                                const __bf16* __restrict__ Bt,
                                                const float* __restrict__ bias,
                                                void* __restrict__ out0,
                                                __bf16* __restrict__ q1,
                                                __bf16* __restrict__ q2,
                                                __bf16* __restrict__ q3,
                                                int N, int K, int kchunk) {
  const int tid = threadIdx.x;
  const int wid = tid >> 6, lane = tid & 63;
  const int g = lane >> 4, r = lane & 15;
  const int wrh = wid >> 2;
  const int wc = (wid & 3) * 64;

  int bm, bn, kbase, zz;
  if constexpr (MODE == 3) {
    const int L = blockIdx.x;
    const int xcd = L & 7, idx = L >> 3;
    zz = xcd >> 1;
    bm = (((xcd & 1) << 3) + (idx >> 2)) * 256;
    bn = (idx & 3) * 256;
    kbase = zz * kchunk;
  } else if constexpr (MAP == 1) {
    const int L = blockIdx.x;
    const int xcd = L & 7, idx = L >> 3;
    bm = (((xcd & 1) << 3) + (idx >> 2)) * 256;
    bn = (((xcd >> 1) << 2) + (idx & 3)) * 256;
    kbase = 0;
    zz = 0;
  } else {
    const int gx = gridDim.x;
    const int nwg = gx * gridDim.y;
    const int orig = blockIdx.y * gx + blockIdx.x;
    const int swz = (orig & 7) * (nwg >> 3) + (orig >> 3);
    const int bn4 = swz & 3;
    const int bmt = (swz >> 2) % gx;
    const int bng = (swz >> 2) / gx;
    bm = bmt * 256;
    bn = (bng * 4 + bn4) * 256;
    kbase = 0;
    zz = 0;
  }

  const int NT = kchunk >> 6;
  const __bf16* Asrc = A + (size_t)bm * K + kbase;
  const __bf16* Bsrc = Bt + (size_t)bn * K + kbase;

  __shared__ __bf16 lds[2][4][8192];  // 128 KB

  f32x4 acc[8][4] = {};
  bf16x8 bfr[4][2];

  auto STG = [&](int ab, int h, int kt) {
    const __bf16* src = (ab ? Bsrc : Asrc) + (size_t)h * 128 * K;
    char* dst = (char*)&lds[kt & 1][ab * 2 + h][0];
#pragma unroll
    for (int gl = 0; gl < 2; ++gl) {
      const int o = gl * 8192 + wid * 1024 + lane * 16;
      const int row = o >> 7;
      const int cbs = (o & 127) ^ (((row >> 2) & 1) << 5);
      gload_lds16((const char*)src + (size_t)row * (K * 2) + kt * 128 + cbs,
                  dst + gl * 8192 + wid * 1024);
    }
  };
  auto DSA = [&](int s, int mi, int kk) -> bf16x8 {
    return *(const bf16x8*)((const char*)&lds[s][wrh][0] + (mi * 16 + r) * 128 +
                            ((kk * 64 + g * 16) ^ ((r & 4) << 3)));
  };
  auto DSB = [&](int s, int nj, int kk) -> bf16x8 {
    const int rt = wc + nj * 16 + r;
    return *(const bf16x8*)((const char*)&lds[s][2 + (rt >> 7)][0] + (rt & 127) * 128 +
                            ((kk * 64 + g * 16) ^ ((r & 4) << 3)));
  };

#define PH(S, Q, STAGE_STMT, WAIT_STMT)                                        \
  {                                                                            \
    if (Q == 0) {                                                              \
      _Pragma("unroll") for (int nj = 0; nj < 4; ++nj) {                       \
        bfr[nj][0] = DSB(S, nj, 0);                                            \
        bfr[nj][1] = DSB(S, nj, 1);                                            \
      }                                                                        \
    }                                                                          \
    bf16x8 a00 = DSA(S, 2 * Q, 0), a01 = DSA(S, 2 * Q, 1);                     \
    bf16x8 a10 = DSA(S, 2 * Q + 1, 0), a11 = DSA(S, 2 * Q + 1, 1);             \
    STAGE_STMT;                                                                \
    WAIT_STMT;                                                                 \
    __builtin_amdgcn_s_barrier();                                              \
    asm volatile("s_waitcnt lgkmcnt(0)" ::: "memory");                         \
    __builtin_amdgcn_s_setprio(1);                                             \
    _Pragma("unroll") for (int nj = 0; nj < 4; ++nj) {                         \
      acc[2 * Q][nj] = MF16(a00, bfr[nj][0], acc[2 * Q][nj], 0, 0, 0);         \
      acc[2 * Q][nj] = MF16(a01, bfr[nj][1], acc[2 * Q][nj], 0, 0, 0);         \
      acc[2 * Q + 1][nj] = MF16(a10, bfr[nj][0], acc[2 * Q + 1][nj], 0, 0, 0); \
      acc[2 * Q + 1][nj] = MF16(a11, bfr[nj][1], acc[2 * Q + 1][nj], 0, 0, 0); \
    }                                                                          \
    __builtin_amdgcn_s_setprio(0);                                             \
    __builtin_amdgcn_s_barrier();                                              \
  }

  STG(1, 0, 0); STG(1, 1, 0); STG(0, 0, 0); STG(0, 1, 0);
  STG(1, 0, 1); STG(1, 1, 1); STG(0, 0, 1);
  asm volatile("s_waitcnt vmcnt(6)" ::: "memory");
  __builtin_amdgcn_s_barrier();

  const int NI = NT >> 1;
  for (int i = 0; i < NI; ++i) {
    const int k2 = 2 * i + 2, k3 = 2 * i + 3;
    const bool nl = (i + 1 < NI);
    PH(0, 0, { STG(0, 1, 2 * i + 1); }, {});
    PH(0, 1, { if (nl) STG(1, 0, k2); }, {});
    PH(0, 2, { if (nl) STG(1, 1, k2); }, {});
    PH(0, 3, { if (nl) STG(0, 0, k2); },
       { if (nl) asm volatile("s_waitcnt vmcnt(6)" ::: "memory");
         else    asm volatile("s_waitcnt vmcnt(0)" ::: "memory"); });
    PH(1, 0, { if (nl) STG(0, 1, k2); }, {});
    PH(1, 1, { if (nl) STG(1, 0, k3); }, {});
    PH(1, 2, { if (nl) STG(1, 1, k3); }, {});
    PH(1, 3, { if (nl) STG(0, 0, k3); },
       { if (nl) asm volatile("s_waitcnt vmcnt(6)" ::: "memory"); });
  }
#undef PH

  const int row0 = bm + wrh * 128 + g * 4;
  const int col0 = bn + wc + r;
#pragma unroll
  for (int mi = 0; mi < 8; ++mi) {
#pragma unroll
    for (int nj = 0; nj < 4; ++nj) {
      const int col = col0 + nj * 16;
      float bv = 0.0f;
      if constexpr (MODE != 3) bv = bias[col];
#pragma unroll
      for (int i4 = 0; i4 < 4; ++i4) {
        const int rowg = row0 + mi * 16 + i4;
        const size_t idx = (size_t)rowg * N + col;
        const float v = acc[mi][nj][i4];
        if constexpr (MODE == 0) {
          ((__bf16*)out0)[idx] = (__bf16)(v + bv);
        } else if constexpr (MODE == 2) {
          const float t = v + bv;
          const float u2 = t * (1.5957691216f + t * t * 0.0713548163f);
          ((__bf16*)out0)[idx] = (__bf16)(t * __builtin_amdgcn_rcpf(1.0f + __expf(-u2)));
        } else {
          if (zz == 0) {
            ((float*)out0)[idx] = v;
          } else {
            __bf16* p = (zz == 1 ? q1 : (zz == 2 ? q2 : q3));
            p[idx] = (__bf16)v;
          }
        }
      }
    }
  }
}

// ---------------- W2 split-K reduce: out = out(p0) + x1 + b2 + p1+p2+p3 ----------------
__global__ __launch_bounds__(256) void reduceW2(const __bf16* __restrict__ p1,
                                                const __bf16* __restrict__ p2,
                                                const __bf16* __restrict__ p3,
                                                const float* __restrict__ x1,
                                                const float* __restrict__ b2,
                                                float* __restrict__ out) {
  const size_t i8 = ((size_t)blockIdx.x * 256 + threadIdx.x) * 8;
  const int col0 = (int)(i8 & 1023);
  bf16x8 a = *(const bf16x8*)(p1 + i8);
  bf16x8 b = *(const bf16x8*)(p2 + i8);
  bf16x8 c = *(const bf16x8*)(p3 + i8);
  float4 o0 = *(const float4*)(out + i8);
  float4 o1 = *(const float4*)(out + i8 + 4);
  const float4 xv0 = *(const float4*)(x1 + i8);
  const float4 xv1 = *(const float4*)(x1 + i8 + 4);
  const float4 bb0 = *(const float4*)(b2 + col0);
  const float4 bb1 = *(const float4*)(b2 + col0 + 4);
  float* op0 = (float*)&o0;
  float* op1 = (float*)&o1;
  const float* xp0 = (const float*)&xv0;
  const float* xp1 = (const float*)&xv1;
  const float* bp0 = (const float*)&bb0;
  const float* bp1 = (const float*)&bb1;
#pragma unroll
  for (int j = 0; j < 4; ++j)
    op0[j] += xp0[j] + bp0[j] + (float)a[j] + (float)b[j] + (float)c[j];
#pragma unroll
  for (int j = 0; j < 4; ++j)
    op1[j] += xp1[j] + bp1[j] + (float)a[4 + j] + (float)b[4 + j] + (float)c[4 + j];
  *(float4*)(out + i8) = o0;
  *(float4*)(out + i8 + 4) = o1;
}

// ---------------- 2-phase 128^2 GEMM (wout): MODE 1 fp32 +resid ----------------
template <int MODE>
__global__ __launch_bounds__(256) void gemm_bt(const __bf16* __restrict__ A,
                                               const __bf16* __restrict__ Bt,
                                               const float* __restrict__ bias,
                                               const float* __restrict__ resid,
                                               void* __restrict__ Cout,
                                               int M, int N, int K) {
  __shared__ __bf16 As[128 * 32];
  __shared__ __bf16 Bs[128 * 32];
  const int tid = threadIdx.x;
  const int wave = tid >> 6, lane = tid & 63;
  const int g = lane >> 4, r = lane & 15;
  const int gx = gridDim.x;
  const int nwg = gx * gridDim.y;
  const int orig = blockIdx.y * gx + blockIdx.x;
  const int swz = (orig & 7) * (nwg >> 3) + (orig >> 3);
  const int bn4 = swz & 3;
  const int bmt = (swz >> 2) % gx;
  const int bng = (swz >> 2) / gx;
  const int bm = bmt * 128;
  const int bn = (bng * 4 + bn4) * 128;
  const int wr = (wave >> 1) * 64, wc = (wave & 1) * 64;
  f32x4 acc[4][4] = {};

  const int off0 = wave * 2048 + lane * 16;
  const int off1 = off0 + 1024;
  const int sr0 = off0 >> 6, sk0 = (off0 & 63) >> 1;
  const int sr1 = off1 >> 6, sk1 = (off1 & 63) >> 1;
  const __bf16* gA0 = A + (size_t)(bm + sr0) * K + sk0;
  const __bf16* gA1 = A + (size_t)(bm + sr1) * K + sk1;
  const __bf16* gB0 = Bt + (size_t)(bn + sr0) * K + sk0;
  const __bf16* gB1 = Bt + (size_t)(bn + sr1) * K + sk1;
  char* lA0 = (char*)As + wave * 2048;
  char* lA1 = lA0 + 1024;
  char* lB0 = (char*)Bs + wave * 2048;
  char* lB1 = lB0 + 1024;

  for (int k0 = 0; k0 < K; k0 += 32) {
    gload_lds16(gA0 + k0, lA0);
    gload_lds16(gA1 + k0, lA1);
    gload_lds16(gB0 + k0, lB0);
    gload_lds16(gB1 + k0, lB1);
    __syncthreads();
    bf16x8 af[4], bf[4];
#pragma unroll
    for (int mi = 0; mi < 4; ++mi)
      af[mi] = *reinterpret_cast<const bf16x8*>(&As[(wr + mi * 16 + r) * 32 + g * 8]);
#pragma unroll
    for (int ni = 0; ni < 4; ++ni)
      bf[ni] = *reinterpret_cast<const bf16x8*>(&Bs[(wc + ni * 16 + r) * 32 + g * 8]);
    __builtin_amdgcn_s_setprio(1);
#pragma unroll
    for (int mi = 0; mi < 4; ++mi)
#pragma unroll
      for (int ni = 0; ni < 4; ++ni)
        acc[mi][ni] = MF16(af[mi], bf[ni], acc[mi][ni], 0, 0, 0);
    __builtin_amdgcn_s_setprio(0);
    __syncthreads();
  }

  const int row0 = bm + wr + 4 * g;
  const int col0 = bn + wc + r;
#pragma unroll
  for (int mi = 0; mi < 4; ++mi) {
#pragma unroll
    for (int ni = 0; ni < 4; ++ni) {
      const int col = col0 + ni * 16;
      const float bv = bias[col];
#pragma unroll
      for (int i = 0; i < 4; ++i) {
        const int row = row0 + mi * 16 + i;
        const size_t idx = (size_t)row * N + col;
        float v = acc[mi][ni][i] + bv;
        if (MODE == 0) {
          ((__bf16*)Cout)[idx] = (__bf16)v;
        } else if (MODE == 1) {
          ((float*)Cout)[idx] = v + resid[idx];
        } else {
          const float u2 = v * (1.5957691216f + v * v * 0.0713548163f);
          const float gl = v * __builtin_amdgcn_rcpf(1.0f + __expf(-u2));
          ((__bf16*)Cout)[idx] = (__bf16)gl;
        }
      }
    }
  }
}

// ---------------- V^T precompute: vtg[bh][d][t] = V[b,t,h,d] ----------------
__global__ __launch_bounds__(256) void vtrans(const __bf16* __restrict__ qkv,
                                              __bf16* __restrict__ vtg) {
  const int bh = blockIdx.y, b = bh >> 4, h = bh & 15;
  const int t0 = blockIdx.x * 64;
  const int tid = threadIdx.x, wave = tid >> 6, lane = tid & 63;
  __shared__ __bf16 tile[64 * 64];
#pragma unroll
  for (int e = 0; e < 2; ++e) {
    const int gid = e * 256 + tid;
    const int row = gid >> 3, d0 = (gid & 7) * 8;
    bf16x8 v = *reinterpret_cast<const bf16x8*>(
        qkv + (size_t)(b * TT + t0 + row) * 3072 + 2048 + h * 64 + d0);
    const int slot = (d0 >> 3) ^ (row & 7);
    *reinterpret_cast<bf16x8*>((char*)tile + row * 128 + slot * 16) = v;
  }
  __syncthreads();
  const int d = lane;
#pragma unroll
  for (int e = 0; e < 2; ++e) {
    const int k0 = (wave * 2 + e) * 8;
    bf16x8 o;
#pragma unroll
    for (int j = 0; j < 8; ++j) {
      const int row = k0 + j;
      o[j] = *(const __bf16*)((const char*)tile + row * 128 +
                              (((d >> 3) ^ (row & 7)) << 4) + (d & 7) * 2);
    }
    *reinterpret_cast<bf16x8*>(&vtg[((size_t)bh * 64 + d) * 2048 + t0 + k0]) = o;
  }
}

// ---------------- stage one 8KB [2][64][32]-panel tile via global_load_lds ----------------
__device__ __forceinline__ void stage_kv(const __bf16* __restrict__ src_row0, int rstride,
                                         int wave, int lane, char* tile) {
#pragma unroll
  for (int qq = 0; qq < 2; ++qq) {
    const int o = wave * 2048 + qq * 1024 + lane * 16;
    const int p = o >> 12, row = (o >> 6) & 63, cb = (o >> 4) & 3;
    gload_lds16(src_row0 + (size_t)row * rstride + p * 32 + cb * 8,
                tile + wave * 2048 + qq * 1024);
  }
}

// ---------------- causal flash attention, q-tile 64, mirror-paired, XCD-local bh ----------------
__global__ __launch_bounds__(256) void attn_fwd(const __bf16* __restrict__ qkv,
                                                const __bf16* __restrict__ vtg,
                                                __bf16* __restrict__ atto) {
  const int orig = blockIdx.y * gridDim.x + blockIdx.x;
  const int swz = (orig & 7) * 64 + (orig >> 3);
  const int bh = swz >> 4;
  const int j = swz & 15;
  const int b = bh >> 4, h = bh & 15;
  const int tid = threadIdx.x;
  const int wave = tid >> 6, lane = tid & 63;
  const int g = lane >> 4, r = lane & 15;

  __shared__ __bf16 Qs[2 * 64 * 32];
  __shared__ __bf16 Ks[2][2 * 64 * 32];
  __shared__ __bf16 Vs[2][2 * 64 * 32];
  __shared__ __bf16 Pl[4][2 * 16 * 32];

  const __bf16* ksrc = qkv + (size_t)(b * TT) * 3072 + 1024 + h * 64;
  const __bf16* vsrc = vtg + (size_t)bh * 64 * 2048;
  const float C2 = 0.18033688011112042f;  // 0.125 * log2(e)

  for (int ph = 0; ph < 2; ++ph) {
    const int qt = ph ? (31 - j) : j;
    const int q0 = qt * 64;
    stage_kv(qkv + (size_t)(b * TT + q0) * 3072 + h * 64, 3072, wave, lane, (char*)Qs);
    stage_kv(ksrc, 3072, wave, lane, (char*)Ks[0]);
    stage_kv(vsrc, 2048, wave, lane, (char*)Vs[0]);

    f32x4 oacc[4] = {};
    float m_s[4], l_s[4];
#pragma unroll
    for (int i = 0; i < 4; ++i) { m_s[i] = -1e30f; l_s[i] = 0.0f; }

    const int nt = qt + 1;
    int cur = 0;
    for (int t = 0; t < nt; ++t) {
      const int kv0 = t * 64;
      __syncthreads();
      if (t + 1 < nt) {
        stage_kv(ksrc + (size_t)(kv0 + 64) * 3072, 3072, wave, lane, (char*)Ks[cur ^ 1]);
        stage_kv(vsrc + kv0 + 64, 2048, wave, lane, (char*)Vs[cur ^ 1]);
      }
      bf16x8 qf[2];
#pragma unroll
      for (int kp = 0; kp < 2; ++kp)
        qf[kp] = *reinterpret_cast<const bf16x8*>(&Qs[kp * 2048 + (wave * 16 + r) * 32 + g * 8]);
      f32x4 s[4];
#pragma unroll
      for (int cn = 0; cn < 4; ++cn) s[cn] = f32x4{0.f, 0.f, 0.f, 0.f};
      __builtin_amdgcn_s_setprio(1);
#pragma unroll
      for (int cn = 0; cn < 4; ++cn)
#pragma unroll
        for (int kp = 0; kp < 2; ++kp) {
          bf16x8 bk = *reinterpret_cast<const bf16x8*>(
              &Ks[cur][kp * 2048 + (cn * 16 + r) * 32 + g * 8]);
          s[cn] = MF16(qf[kp], bk, s[cn], 0, 0, 0);
        }
      __builtin_amdgcn_s_setprio(0);
      const int rowg = q0 + wave * 16 + 4 * g;
      float pm[4];
#pragma unroll
      for (int i = 0; i < 4; ++i) pm[i] = -1e30f;
      if (kv0 + 63 > q0 + wave * 16) {
#pragma unroll
        for (int cn = 0; cn < 4; ++cn) {
          const int colg = kv0 + cn * 16 + r;
#pragma unroll
          for (int i = 0; i < 4; ++i) {
            float v = s[cn][i] * C2;
            v = (colg > rowg + i) ? -1e30f : v;
            s[cn][i] = v;
            pm[i] = fmaxf(pm[i], v);
          }
        }
      } else {
#pragma unroll
        for (int cn = 0; cn < 4; ++cn)
#pragma unroll
          for (int i = 0; i < 4; ++i) {
            const float v = s[cn][i] * C2;
            s[cn][i] = v;
            pm[i] = fmaxf(pm[i], v);
          }
      }
      const int upd = __any((pm[0] > m_s[0] + 8.0f) || (pm[1] > m_s[1] + 8.0f) ||
                            (pm[2] > m_s[2] + 8.0f) || (pm[3] > m_s[3] + 8.0f));
      if (upd) {
#pragma unroll
        for (int i = 0; i < 4; ++i) {
          pm[i] = fmaxf(pm[i], __shfl_xor(pm[i], 1));
          pm[i] = fmaxf(pm[i], __shfl_xor(pm[i], 2));
          pm[i] = fmaxf(pm[i], __shfl_xor(pm[i], 4));
          pm[i] = fmaxf(pm[i], __shfl_xor(pm[i], 8));
          const float mn = fmaxf(m_s[i], pm[i]);
          const float sf = __builtin_amdgcn_exp2f(m_s[i] - mn);
          m_s[i] = mn;
          l_s[i] *= sf;
#pragma unroll
          for (int ni = 0; ni < 4; ++ni) oacc[ni][i] *= sf;
        }
      }
#pragma unroll
      for (int cn = 0; cn < 4; ++cn)
#pragma unroll
        for (int i = 0; i < 4; ++i) {
          const float p = __builtin_amdgcn_exp2f(s[cn][i] - m_s[i]);
          s[cn][i] = p;
          l_s[i] += p;
        }
#pragma unroll
      for (int cn = 0; cn < 4; ++cn)
#pragma unroll
        for (int i = 0; i < 4; ++i) {
          const int row = 4 * g + i;
          const int byteoff = (cn >> 1) * 1024 +
              ((row * 64 + (cn & 1) * 32 + r * 2) ^ ((row & 7) << 4));
          *(__bf16*)((char*)&Pl[wave][0] + byteoff) = (__bf16)s[cn][i];
        }
      bf16x8 pa[2];
#pragma unroll
      for (int kp = 0; kp < 2; ++kp) {
        const int byteoff = kp * 1024 + ((r * 64 + g * 16) ^ ((r & 7) << 4));
        pa[kp] = *reinterpret_cast<const bf16x8*>((const char*)&Pl[wave][0] + byteoff);
      }
      __builtin_amdgcn_s_setprio(1);
#pragma unroll
      for (int ni = 0; ni < 4; ++ni)
#pragma unroll
        for (int kp = 0; kp < 2; ++kp) {
          bf16x8 bv = *reinterpret_cast<const bf16x8*>(
              &Vs[cur][kp * 2048 + (ni * 16 + r) * 32 + g * 8]);
          oacc[ni] = MF16(pa[kp], bv, oacc[ni], 0, 0, 0);
        }
      __builtin_amdgcn_s_setprio(0);
      cur ^= 1;
    }

#pragma unroll
    for (int i = 0; i < 4; ++i) {
      float l = l_s[i];
      l += __shfl_xor(l, 1);
      l += __shfl_xor(l, 2);
      l += __shfl_xor(l, 4);
      l += __shfl_xor(l, 8);
      const float inv = 1.0f / l;
      const size_t rowo = (size_t)(b * TT + q0 + wave * 16 + 4 * g + i) * DD + h * 64;
#pragma unroll
      for (int ni = 0; ni < 4; ++ni)
        atto[rowo + ni * 16 + r] = (__bf16)(oacc[ni][i] * inv);
    }
    __syncthreads();
  }
}

extern "C" void kernel_launch(void* const* d_in, const int* in_sizes, int n_in,
                              void* d_out, int out_size, void* d_ws, size_t ws_size,
                              hipStream_t stream) {
  const float* x     = (const float*)d_in[0];
  const float* ln1_g = (const float*)d_in[1];
  const float* ln1_b = (const float*)d_in[2];
  const float* Wqkv  = (const float*)d_in[3];
  const float* bqkv  = (const float*)d_in[4];
  const float* Wout  = (const float*)d_in[5];
  const float* bout  = (const float*)d_in[6];
  const float* ln2_g = (const float*)d_in[7];
  const float* ln2_b = (const float*)d_in[8];
  const float* W1    = (const float*)d_in[9];
  const float* b1    = (const float*)d_in[10];
  const float* W2    = (const float*)d_in[11];
  const float* b2    = (const float*)d_in[12];
  float* out = (float*)d_out;

  char* ws = (char*)d_ws;
  const size_t MB = 1024 * 1024;
  __bf16* WqkvT = (__bf16*)(ws);             // 0-6 MB
  __bf16* WoutT = (__bf16*)(ws + 6 * MB);    // 6-8 MB
  __bf16* W1T   = (__bf16*)(ws + 8 * MB);    // 8-16 MB
  __bf16* W2T   = (__bf16*)(ws + 16 * MB);   // 16-24 MB
  float*  x1    = (float*)(ws + 24 * MB);    // 24-40 MB fp32 (written by wout gemm)
  __bf16* vtg   = (__bf16*)(ws + 24 * MB);   // 24-32 MB — dead before x1 written
  __bf16* hbuf  = (__bf16*)(ws + 40 * MB);   // 40-48 MB (ln1/ln2 out)
  __bf16* qkvb  = (__bf16*)(ws + 48 * MB);   // 48-72 MB
  __bf16* atto  = (__bf16*)(ws + 72 * MB);   // 72-80 MB
  __bf16* mlp1  = (__bf16*)(ws + 48 * MB);   // 48-80 MB (aliases qkvb+atto, dead by then)
  __bf16* p1b   = (__bf16*)(ws);             // 0-8 MB   (WqkvT/WoutT dead)
  __bf16* p2b   = (__bf16*)(ws + 8 * MB);    // 8-16 MB  (W1T dead)
  __bf16* p3b   = (__bf16*)(ws + 40 * MB);   // 40-48 MB (hbuf dead after W1 gemm)

  // weight prep (single launch)
  castAll<<<3072, 256, 0, stream>>>(Wqkv, Wout, W1, W2, WqkvT, WoutT, W1T, W2T);

  // attention path
  ln_fwd<<<1024, 256, 0, stream>>>(x, ln1_g, ln1_b, hbuf);
  gemm8<0><<<dim3(16, 12), 512, 0, stream>>>(hbuf, WqkvT, bqkv, qkvb,
                                             nullptr, nullptr, nullptr, 3072, 1024, 1024);
  vtrans<<<dim3(32, 32), 256, 0, stream>>>(qkvb, vtg);
  attn_fwd<<<dim3(16, 32), 256, 0, stream>>>(qkvb, vtg, atto);
  gemm_bt<1><<<dim3(32, 8), 256, 0, stream>>>(atto, WoutT, bout, x, x1, 4096, 1024, 1024);

  // MLP path (W1 uses producer map so each XCD's mlp1 slice stays in its L2 for W2)
  ln_fwd<<<1024, 256, 0, stream>>>(x1, ln2_g, ln2_b, hbuf);
  gemm8<2, 1><<<256, 512, 0, stream>>>(hbuf, W1T, b1, mlp1,
                                       nullptr, nullptr, nullptr, 4096, 1024, 1024);
  gemm8<3><<<dim3(256, 1), 512, 0, stream>>>(mlp1, W2T, nullptr, out,
                                             p1b, p2b, p3b, 1024, 4096, 1024);
  reduceW2<<<2048, 256, 0, stream>>>(p1b, p2b, p3b, x1, b2, out);
}